// Round 6
// baseline (465.482 us; speedup 1.0000x reference)
//
#include <hip/hip_runtime.h>
#include <cstdint>
#include <cstddef>

// ---------- types & helpers ----------
typedef __bf16 bf16x8 __attribute__((ext_vector_type(8)));
typedef float  f32x4  __attribute__((ext_vector_type(4)));
typedef unsigned short u16x4 __attribute__((ext_vector_type(4)));

typedef __attribute__((address_space(1))) void* gas1_t;
typedef __attribute__((address_space(3))) void* las3_t;

__device__ __forceinline__ unsigned short f2bf(float f) {
  union { float f; unsigned u; } v; v.f = f;
  unsigned r = v.u + 0x7fffu + ((v.u >> 16) & 1u);   // RNE
  return (unsigned short)(r >> 16);
}
__device__ __forceinline__ float bf2f(unsigned short h) {
  union { unsigned u; float f; } v; v.u = ((unsigned)h) << 16;
  return v.f;
}

// ---------- problem constants ----------
constexpr int Bc = 4, Lc = 8192, Dc = 1024, NSAMP = 2048;
constexpr int ROWS = Bc * Lc;        // 32768
constexpr int NSEL = Bc * NSAMP;     // 8192
constexpr long long Y_ELEMS = (long long)ROWS * Dc;          // 33554432
constexpr long long GRAD_OFF = Y_ELEMS;                      // grad after y
constexpr long long LOSS_OFF = GRAD_OFF + (long long)Dc*Dc;  // 34603008

constexpr int BM = 128, BN = 128, BK = 64;

// ============================================================================
// y-GEMM: y = x @ M^T + bias. A = fp32 x, reg-staged with inline bf16 convert
// (replaces the standalone 192-MB cvt pass + 64-MB xb buffer entirely).
// B (mb, bf16) stays on the async global_load_lds path.
// sA layout: row-major [128][64] bf16 — identical to the gload_lds layout, so
// the compute loop is byte-for-byte the proven m97-structure inner loop.
// ============================================================================
__global__ __launch_bounds__(256)
void gemm_y(const float* __restrict__ A,            // x fp32 [M][K]
            const unsigned short* __restrict__ B,   // mb bf16 [N][K]
            float* __restrict__ Cf,
            const float* __restrict__ bias,
            int M, int N, int K) {
  __shared__ unsigned short sA[BM * BK];   // 16 KB
  __shared__ unsigned short sB[BN * BK];   // 16 KB
  const int tid  = threadIdx.x;
  const int lane = tid & 63;
  const int wave = tid >> 6;
  const int wm = wave >> 1, wn = wave & 1;
  const int q = lane >> 4, r16 = lane & 15;

  // T1 bijective XCD swizzle (nwg = 2048, % 8 == 0)
  const int gx   = gridDim.x;
  const int nwg  = gx * gridDim.y;
  const int orig = blockIdx.y * gx + blockIdx.x;
  const int swz  = (orig & 7) * (nwg >> 3) + (orig >> 3);
  const int m0 = (swz / gx) * BM;
  const int n0 = (swz % gx) * BN;

  const int lrow = lane >> 3;
  const int lcol = (lane & 7) * 8;
  const int arow = tid >> 4;          // 0..15: staged row within 16-row slab
  const int acol = (tid & 15) * 4;    // fp32 col (16 B per thread)

  f32x4 acc[4][4] = {};

  for (int k0 = 0; k0 < K; k0 += BK) {
    // fp32 A loads first (oldest in vmcnt queue -> converts don't wait on B)
    f32x4 av[8];
#pragma unroll
    for (int it = 0; it < 8; ++it)
      av[it] = *(const f32x4*)(A + (size_t)(m0 + arow + it * 16) * K + k0 + acol);
    // B via async global->LDS
#pragma unroll
    for (int j = 0; j < 4; ++j) {
      const int c = wave * 4 + j;
      const unsigned short* gb = B + (size_t)(n0 + c * 8 + lrow) * K + k0 + lcol;
      __builtin_amdgcn_global_load_lds((gas1_t)(void*)gb, (las3_t)(sB + c * 512), 16, 0, 0);
    }
    // convert + LDS write (2-way bank alias on b64 writes = free)
#pragma unroll
    for (int it = 0; it < 8; ++it) {
      u16x4 o;
      o.x = f2bf(av[it].x); o.y = f2bf(av[it].y);
      o.z = f2bf(av[it].z); o.w = f2bf(av[it].w);
      *(u16x4*)(sA + (arow + it * 16) * BK + acol) = o;
    }
    __syncthreads();
#pragma unroll
    for (int kk = 0; kk < BK; kk += 32) {
      bf16x8 af[4], bfv[4];
#pragma unroll
      for (int mi = 0; mi < 4; ++mi)
        af[mi] = *(const bf16x8*)(sA + (size_t)(wm*64 + mi*16 + r16) * BK + kk + q*8);
#pragma unroll
      for (int ni = 0; ni < 4; ++ni)
        bfv[ni] = *(const bf16x8*)(sB + (size_t)(wn*64 + ni*16 + r16) * BK + kk + q*8);
#pragma unroll
      for (int mi = 0; mi < 4; ++mi)
#pragma unroll
        for (int ni = 0; ni < 4; ++ni)
          acc[mi][ni] = __builtin_amdgcn_mfma_f32_16x16x32_bf16(af[mi], bfv[ni], acc[mi][ni], 0, 0, 0);
    }
    __syncthreads();
  }

  // epilogue: lane holds C[row = q*4+r][col = r16]; ni innermost for full-line WC
  const int row0 = m0 + wm*64 + q*4;
  const int col0 = n0 + wn*64 + r16;
  float bv[4];
#pragma unroll
  for (int ni = 0; ni < 4; ++ni) bv[ni] = bias[col0 + ni*16];
#pragma unroll
  for (int mi = 0; mi < 4; ++mi) {
#pragma unroll
    for (int r = 0; r < 4; ++r) {
      const int row = row0 + mi*16 + r;
      const size_t base = (size_t)row * N + col0;
#pragma unroll
      for (int ni = 0; ni < 4; ++ni)
        __builtin_nontemporal_store(acc[mi][ni][r] + bv[ni], &Cf[base + (size_t)ni * 16]);
    }
  }
}

// ---------- 128x128 B^T GEMM, bf16 in ----------
// MODE 5: bf16 store ((ushort*)Cf)[o] = bf16(acc)     (M = W@decorr)
// MODE 7: split-K partial store (no atomics):          (G = xsT xsT^T)
//         Cf[(z*64 + tile)*16384 + lr*128 + lc] = acc
template<int MODE>
__global__ void gemm_bt(const unsigned short* __restrict__ A,
                        const unsigned short* __restrict__ B,
                        float* __restrict__ Cf,
                        int M, int N, int K, int kchunk) {
  __shared__ unsigned short sA[BM * BK];   // 16 KB
  __shared__ unsigned short sB[BN * BK];   // 16 KB
  const int tid  = threadIdx.x;
  const int lane = tid & 63;
  const int wave = tid >> 6;
  const int wm = wave >> 1, wn = wave & 1;
  const int q = lane >> 4, r16 = lane & 15;

  // T1 bijective XCD swizzle (nwg % 8 == 0 for all launches)
  const int gx   = gridDim.x;
  const int nwg  = gx * gridDim.y;
  const int orig = blockIdx.y * gx + blockIdx.x;
  const int swz  = (orig & 7) * (nwg >> 3) + (orig >> 3);
  const int m0 = (swz / gx) * BM;
  const int n0 = (swz % gx) * BN;
  const int kb = blockIdx.z * kchunk;

  const int lrow = lane >> 3;
  const int lcol = (lane & 7) * 8;

  f32x4 acc[4][4] = {};

  for (int k0 = kb; k0 < kb + kchunk; k0 += BK) {
#pragma unroll
    for (int j = 0; j < 4; ++j) {
      const int c = wave * 4 + j;
      const int row = c * 8 + lrow;
      const unsigned short* ga = A + (size_t)(m0 + row) * K + k0 + lcol;
      __builtin_amdgcn_global_load_lds((gas1_t)(void*)ga, (las3_t)(sA + c * 512), 16, 0, 0);
      const unsigned short* gb = B + (size_t)(n0 + row) * K + k0 + lcol;
      __builtin_amdgcn_global_load_lds((gas1_t)(void*)gb, (las3_t)(sB + c * 512), 16, 0, 0);
    }
    __syncthreads();
#pragma unroll
    for (int kk = 0; kk < BK; kk += 32) {
      bf16x8 af[4], bfv[4];
#pragma unroll
      for (int mi = 0; mi < 4; ++mi)
        af[mi] = *(const bf16x8*)(sA + (size_t)(wm*64 + mi*16 + r16) * BK + kk + q*8);
#pragma unroll
      for (int ni = 0; ni < 4; ++ni)
        bfv[ni] = *(const bf16x8*)(sB + (size_t)(wn*64 + ni*16 + r16) * BK + kk + q*8);
#pragma unroll
      for (int mi = 0; mi < 4; ++mi)
#pragma unroll
        for (int ni = 0; ni < 4; ++ni)
          acc[mi][ni] = __builtin_amdgcn_mfma_f32_16x16x32_bf16(af[mi], bfv[ni], acc[mi][ni], 0, 0, 0);
    }
    __syncthreads();
  }

  const int row0 = m0 + wm*64 + q*4;
  const int col0 = n0 + wn*64 + r16;
  float* dst7 = nullptr;
  if (MODE == 7)
    dst7 = Cf + ((size_t)blockIdx.z * 64 + (size_t)(m0 >> 7) * 8 + (n0 >> 7)) * 16384;
#pragma unroll
  for (int mi = 0; mi < 4; ++mi) {
#pragma unroll
    for (int r = 0; r < 4; ++r) {
      const int row = row0 + mi*16 + r;
#pragma unroll
      for (int ni = 0; ni < 4; ++ni) {
        const int col = col0 + ni*16;
        float v = acc[mi][ni][r];
        if (MODE == 5)      ((unsigned short*)Cf)[(size_t)row * N + col] = f2bf(v);
        else                dst7[(size_t)(row - m0) * 128 + (col - n0)] = v;
      }
    }
  }
}

// ---------- fused xs pass: GEMM (ab @ dT^T) + diag correction + stats + bf16 transpose ----
__global__ __launch_bounds__(256)
void xs_gemm_fused(const unsigned short* __restrict__ A,   // ab [NSEL][Dc]
                   const unsigned short* __restrict__ B,   // dT [Dc][Dc]
                   const float* __restrict__ cvec,
                   unsigned short* __restrict__ xsT,       // [Dc][NSEL]
                   float* __restrict__ m2sum, float* __restrict__ s1g,
                   float* __restrict__ s2g,
                   int M, int N, int K) {
  __shared__ __attribute__((aligned(16))) unsigned short shm[128 * 136];  // 34816 B
  unsigned short* sA = shm;            // staging A [128*64] = 16 KB
  unsigned short* sB = shm + 8192;     // staging B [128*64] = 16 KB
  const int tid  = threadIdx.x;
  const int lane = tid & 63;
  const int wave = tid >> 6;
  const int wm = wave >> 1, wn = wave & 1;
  const int q = lane >> 4, r16 = lane & 15;

  const int gx   = gridDim.x;
  const int nwg  = gx * gridDim.y;
  const int orig = blockIdx.y * gx + blockIdx.x;
  const int swz  = (orig & 7) * (nwg >> 3) + (orig >> 3);
  const int m0 = (swz / gx) * BM;   // sample tile base
  const int n0 = (swz % gx) * BN;   // feature tile base

  const int lrow = lane >> 3;
  const int lcol = (lane & 7) * 8;

  f32x4 acc[4][4] = {};

  for (int k0 = 0; k0 < K; k0 += BK) {
#pragma unroll
    for (int j = 0; j < 4; ++j) {
      const int c = wave * 4 + j;
      const int row = c * 8 + lrow;
      const unsigned short* ga = A + (size_t)(m0 + row) * K + k0 + lcol;
      __builtin_amdgcn_global_load_lds((gas1_t)(void*)ga, (las3_t)(sA + c * 512), 16, 0, 0);
      const unsigned short* gb = B + (size_t)(n0 + row) * K + k0 + lcol;
      __builtin_amdgcn_global_load_lds((gas1_t)(void*)gb, (las3_t)(sB + c * 512), 16, 0, 0);
    }
    __syncthreads();
#pragma unroll
    for (int kk = 0; kk < BK; kk += 32) {
      bf16x8 af[4], bfv[4];
#pragma unroll
      for (int mi = 0; mi < 4; ++mi)
        af[mi] = *(const bf16x8*)(sA + (size_t)(wm*64 + mi*16 + r16) * BK + kk + q*8);
#pragma unroll
      for (int ni = 0; ni < 4; ++ni)
        bfv[ni] = *(const bf16x8*)(sB + (size_t)(wn*64 + ni*16 + r16) * BK + kk + q*8);
#pragma unroll
      for (int mi = 0; mi < 4; ++mi)
#pragma unroll
        for (int ni = 0; ni < 4; ++ni)
          acc[mi][ni] = __builtin_amdgcn_mfma_f32_16x16x32_bf16(af[mi], bfv[ni], acc[mi][ni], 0, 0, 0);
    }
    __syncthreads();
  }

  // ---- epilogue: correction + bf16 tile into LDS (pitch 136 kills stride conflicts)
  const int lr0 = wm*64 + q*4;
  const int lc0 = wn*64 + r16;
  float cvl[4];
#pragma unroll
  for (int ni = 0; ni < 4; ++ni) cvl[ni] = cvec[n0 + lc0 + ni*16];
#pragma unroll
  for (int mi = 0; mi < 4; ++mi) {
#pragma unroll
    for (int r = 0; r < 4; ++r) {
      const int lr = lr0 + mi*16 + r;
      const size_t arow = (size_t)(m0 + lr) * K;
#pragma unroll
      for (int ni = 0; ni < 4; ++ni) {
        const int lc = lc0 + ni*16;
        float v = acc[mi][ni][r] + bf2f(A[arow + n0 + lc]) * cvl[ni];
        shm[lr * 136 + lc] = f2bf(v);
      }
    }
  }
  __syncthreads();

  // ---- stats from LDS
  if (tid < 128) {
    float s1 = 0.f, s2 = 0.f;
#pragma unroll 8
    for (int c = 0; c < 128; ++c) {
      float v = bf2f(shm[tid * 136 + c]); float v2 = v * v;
      s1 += v2; s2 += v2 * v2;
    }
    atomicAdd(&s1g[m0 + tid], s1);
    atomicAdd(&s2g[m0 + tid], s2);
  } else {
    const int col = tid - 128;
    float cs = 0.f;
#pragma unroll 8
    for (int r = 0; r < 128; ++r) {
      float v = bf2f(shm[r * 136 + col]); cs += v * v;
    }
    atomicAdd(&m2sum[n0 + col], cs);
  }

  // ---- transposed coalesced write
  const int fi = tid >> 1, hh = tid & 1;
  unsigned short* dst = xsT + (size_t)(n0 + fi) * M + m0 + hh * 64;
#pragma unroll
  for (int j = 0; j < 64; j += 4) {
    u16x4 v;
    v.x = shm[(hh*64 + j + 0) * 136 + fi];
    v.y = shm[(hh*64 + j + 1) * 136 + fi];
    v.z = shm[(hh*64 + j + 2) * 136 + fi];
    v.w = shm[(hh*64 + j + 3) * 136 + fi];
    *(u16x4*)(dst + j) = v;
  }
}

// ---------- gather sampled tokens from fp32 x, convert inline: ab[blk][:] = bf16(x[b][idx][:]) ----
__global__ void gather_rows(const float* __restrict__ x, const int* __restrict__ idx,
                            unsigned short* __restrict__ out) {
  const int blk = blockIdx.x;            // 0..8191 = b*2048+n
  const int b = blk >> 11, n = blk & 2047;
  const int row = idx[b * NSAMP + n];
  const float* src = x + ((size_t)b * Lc + row) * Dc;
  unsigned short* dst = out + (size_t)blk * Dc;
  const int c = threadIdx.x * 4;
  f32x4 v = *(const f32x4*)(src + c);
  u16x4 o;
  o.x = f2bf(v.x); o.y = f2bf(v.y); o.z = f2bf(v.z); o.w = f2bf(v.w);
  *(u16x4*)(dst + c) = o;
}

// ---------- fused prep: wb = bf16(W); dT = bf16(decorr^T); cv = diag residual ----------
__global__ void prep_wdt(const float* __restrict__ W, const float* __restrict__ dc,
                         unsigned short* __restrict__ wb, unsigned short* __restrict__ dT,
                         float* __restrict__ cvec) {
  __shared__ float tile[64][65];
  const int r0 = blockIdx.y * 64, c0 = blockIdx.x * 64;
  const int t = threadIdx.x;
  const int c = t & 63, r4 = t >> 6;
#pragma unroll
  for (int j = 0; j < 16; ++j) {
    const int r = j * 4 + r4;
    const size_t o = (size_t)(r0 + r) * Dc + c0 + c;
    wb[o] = f2bf(W[o]);
    tile[r][c] = dc[o];
  }
  __syncthreads();
  if (blockIdx.x == blockIdx.y && t < 64) {
    const float v = tile[t][t];
    cvec[c0 + t] = v - bf2f(f2bf(v));
  }
  const int i = t >> 2, p = t & 3;
  unsigned short* dst = dT + (size_t)(c0 + i) * Dc + r0 + p * 16;
#pragma unroll
  for (int j = 0; j < 16; j += 4) {
    u16x4 v;
    v.x = f2bf(tile[p*16 + j + 0][i]);
    v.y = f2bf(tile[p*16 + j + 1][i]);
    v.z = f2bf(tile[p*16 + j + 2][i]);
    v.w = f2bf(tile[p*16 + j + 3][i]);
    *(u16x4*)(dst + j) = v;
  }
}

// ---------- grad writeout: sum 8 split-K partials; off-diag 0.5*G/N, diag 0.5*(m2-1) ----
__global__ void grad_write(const float* __restrict__ Gp, const float* __restrict__ m2sum,
                           float* __restrict__ out) {
  const int i = blockIdx.x * 256 + threadIdx.x;   // 0..1048575
  const int r = i >> 10, c = i & 1023;
  const size_t tidx = (size_t)((r >> 7) * 8 + (c >> 7));
  const float* base = Gp + tidx * 16384 + (size_t)(r & 127) * 128 + (c & 127);
  float s = 0.f;
#pragma unroll
  for (int z = 0; z < 8; ++z) s += base[(size_t)z * 64 * 16384];
  float g = s * (0.5f / (float)NSEL);
  if (r == c) g = 0.5f * (m2sum[r] * (1.0f / (float)NSEL) - 1.0f);
  __builtin_nontemporal_store(g, &out[i]);
}

// ---------- losses: corr=(Σs1²−Σs2)/denom, white=(Σs2−2Σs1+N·d)/denom ----------
__global__ void finalize_losses(const float* __restrict__ s1g, const float* __restrict__ s2g,
                                float* __restrict__ out2) {
  __shared__ double sa[256], sb[256], sc[256];
  double a = 0, b = 0, c = 0;
  for (int n = threadIdx.x; n < NSEL; n += 256) {
    double s1 = s1g[n], s2 = s2g[n];
    a += s1 * s1; b += s2; c += s1;
  }
  const int t = threadIdx.x;
  sa[t] = a; sb[t] = b; sc[t] = c;
  __syncthreads();
  for (int s = 128; s > 0; s >>= 1) {
    if (t < s) { sa[t] += sa[t+s]; sb[t] += sb[t+s]; sc[t] += sc[t+s]; }
    __syncthreads();
  }
  if (t == 0) {
    const double denom = (double)NSEL * (double)Dc * (double)Dc;
    const double cnt   = (double)NSEL * (double)Dc;
    out2[0] = (float)((sa[0] - sb[0]) / denom);
    out2[1] = (float)((sb[0] - 2.0 * sc[0] + cnt) / denom);
  }
}

extern "C" void kernel_launch(void* const* d_in, const int* in_sizes, int n_in,
                              void* d_out, int out_size, void* d_ws, size_t ws_size,
                              hipStream_t stream) {
  const float* x      = (const float*)d_in[0];
  const float* W      = (const float*)d_in[1];
  const float* bias   = (const float*)d_in[2];
  const float* decorr = (const float*)d_in[3];
  const int*   sidx   = (const int*)d_in[4];
  float* out = (float*)d_out;

  // workspace layout (bytes) — xb (64 MB) is GONE; Gp replaces atomic G
  char* w = (char*)d_ws;
  constexpr size_t SZ_AB  = (size_t)NSEL * Dc * 2;            // gathered sel bf16 16 MB
  constexpr size_t SZ_DT  = (size_t)Dc * Dc * 2;              // decorr^T bf16      2 MB
  constexpr size_t SZ_WB  = (size_t)Dc * Dc * 2;              // W bf16             2 MB
  constexpr size_t SZ_MB  = (size_t)Dc * Dc * 2;              // M bf16             2 MB
  constexpr size_t SZ_XST = (size_t)Dc * NSEL * 2;            // xs^T bf16         16 MB
  constexpr size_t SZ_CV  = (size_t)Dc * 4;
  constexpr size_t SZ_GP  = (size_t)8 * 64 * 128 * 128 * 4;   // G partials        32 MB
  constexpr size_t SZ_M2  = (size_t)Dc * 4;
  constexpr size_t SZ_S1  = (size_t)NSEL * 4;
  constexpr size_t SZ_S2  = (size_t)NSEL * 4;

  size_t off = 0;
  unsigned short* ab  = (unsigned short*)(w + off); off += SZ_AB;
  unsigned short* dT  = (unsigned short*)(w + off); off += SZ_DT;
  unsigned short* wb  = (unsigned short*)(w + off); off += SZ_WB;
  unsigned short* mb  = (unsigned short*)(w + off); off += SZ_MB;
  unsigned short* xsT = (unsigned short*)(w + off); off += SZ_XST;
  float*          cv  = (float*)(w + off);          off += SZ_CV;
  float*          Gp  = (float*)(w + off);          off += SZ_GP;
  char*           zbase = w + off;                   // zeroed region (stats only)
  float*          m2s = (float*)(w + off);          off += SZ_M2;
  float*          s1g = (float*)(w + off);          off += SZ_S1;
  float*          s2g = (float*)(w + off);          off += SZ_S2;
  const size_t zbytes = SZ_M2 + SZ_S1 + SZ_S2;      // 68 KB (was 12 MB)

  (void)hipMemsetAsync(zbase, 0, zbytes, stream);

  // prep (W/decorr) + gather (reads fp32 x directly, converts inline)
  prep_wdt<<<dim3(16, 16), 256, 0, stream>>>(W, decorr, wb, dT, cv);
  gather_rows<<<NSEL, 256, 0, stream>>>(x, sidx, ab);

  // M = W @ decorr : direct bf16 epilogue
  gemm_bt<5><<<dim3(Dc/BN, Dc/BM, 1), 256, 0, stream>>>(wb, dT, (float*)mb, Dc, Dc, Dc, Dc);

  // y = x @ M^T + bias : fp32-A reg-staged (no cvt pass, no xb)
  gemm_y<<<dim3(Dc/BN, ROWS/BM), 256, 0, stream>>>(x, mb, out, bias, ROWS, Dc, Dc);

  // xs fused: GEMM + diag correction + stats + bf16 transpose
  xs_gemm_fused<<<dim3(Dc/BN, NSEL/BM), 256, 0, stream>>>(ab, dT, cv, xsT, m2s, s1g, s2g,
                                                          NSEL, Dc, Dc);

  // G = xs^T xs : full 64 tiles, split-K=8 partial stores (no atomics)
  gemm_bt<7><<<dim3(Dc/BN, Dc/BM, 8), 256, 0, stream>>>(xsT, xsT, Gp, Dc, Dc, NSEL, NSEL/8);

  // outputs
  grad_write<<<Dc*Dc / 256, 256, 0, stream>>>(Gp, m2s, out + GRAD_OFF);
  finalize_losses<<<1, 256, 0, stream>>>(s1g, s2g, out + LOSS_OFF);
}